// Round 2
// baseline (2161.614 us; speedup 1.0000x reference)
//
#include <hip/hip_runtime.h>
#include <cmath>
#include <type_traits>

// ChEst: shared-weight Elman RNN, H=8192, 64 steps.
//   U = x @ W_ih^T + b   (one f16-MFMA GEMM, written into d_out)
//   h_t = tanh(U[t] + W_hh @ h_{t-1})  (64 sequential matvec kernels, fp16 W_hh
//                                       streamed from L3: 128 MiB/step)
// d_ws layout (fast path, needs ~129 MiB): [W_hh fp16 128MiB][x fp16 1MiB]

#define HDIM 8192
#define NSTEP 64

typedef _Float16 f16;
typedef _Float16 f16x2 __attribute__((ext_vector_type(2)));
typedef _Float16 f16x4 __attribute__((ext_vector_type(4)));
typedef _Float16 f16x8 __attribute__((ext_vector_type(8)));
typedef __fp16 fp16x2_raw __attribute__((ext_vector_type(2)));
typedef float f32x4 __attribute__((ext_vector_type(4)));

#if defined(__has_builtin)
#if __has_builtin(__builtin_amdgcn_fdot2)
#define HAS_FDOT2 1
#endif
#endif

// cvt_pkrtz returns an __fp16-based vector; bit-cast to our _Float16 vector.
__device__ __forceinline__ f16x2 pkrtz(float a, float b) {
  fp16x2_raw r = __builtin_amdgcn_cvt_pkrtz(a, b);
  return __builtin_bit_cast(f16x2, r);
}

__device__ __forceinline__ float dot2acc(f16 a0, f16 a1, f16 b0, f16 b1, float c) {
#ifdef HAS_FDOT2
  f16x2 a = {a0, a1}, b = {b0, b1};
  return __builtin_amdgcn_fdot2(a, b, c, false);
#else
  return c + (float)a0 * (float)b0 + (float)a1 * (float)b1;
#endif
}

// ---------------- fp32 -> fp16 convert (grid-stride, vectorized) -------------
__global__ void cvt_f16_kernel(const float* __restrict__ src,
                               f16* __restrict__ dst, int n4) {
  int idx = blockIdx.x * blockDim.x + threadIdx.x;
  int stride = gridDim.x * blockDim.x;
  for (int i = idx; i < n4; i += stride) {
    f32x4 v = ((const f32x4*)src)[i];
    f16x4 h;
    h[0] = (f16)v[0]; h[1] = (f16)v[1]; h[2] = (f16)v[2]; h[3] = (f16)v[3];
    ((f16x4*)dst)[i] = h;
  }
}

// ---------------- Phase 1: U = x @ W_ih^T + b  (into d_out) ------------------
// grid = 8192/16 = 512 blocks x 256 thr (4 waves). Block owns 16 output cols
// (rows of W_ih); wave w owns m-subtile w (16 of the 64 x-rows).
// mfma_f32_16x16x32_f16: A[m=lane&15][k=q*8+j], B[n=lane&15][k=q*8+j],
// C: col=lane&15, row=q*4+reg  (guide §3, m89-verified layout).
template <bool XF16>
__global__ __launch_bounds__(256) void gemm_u_kernel(
    const float* __restrict__ x, const f16* __restrict__ x16,
    const float* __restrict__ Wih, const float* __restrict__ b,
    float* __restrict__ out) {
  const int wave = threadIdx.x >> 6;
  const int lane = threadIdx.x & 63;
  const int r = lane & 15, q = lane >> 4;
  const int n0 = blockIdx.x * 16;
  const int m0 = wave * 16;
  const float* wrow = Wih + (size_t)(n0 + r) * HDIM;
  f32x4 acc = {0.f, 0.f, 0.f, 0.f};
#pragma unroll 2
  for (int k0 = 0; k0 < HDIM; k0 += 32) {
    const int kb = k0 + q * 8;
    f16x8 fa;
    if constexpr (XF16) {
      fa = *(const f16x8*)(x16 + (size_t)(m0 + r) * HDIM + kb);
    } else {
      f32x4 a0 = *(const f32x4*)(x + (size_t)(m0 + r) * HDIM + kb);
      f32x4 a1 = *(const f32x4*)(x + (size_t)(m0 + r) * HDIM + kb + 4);
      f16x2 p0 = pkrtz(a0[0], a0[1]);
      f16x2 p1 = pkrtz(a0[2], a0[3]);
      f16x2 p2 = pkrtz(a1[0], a1[1]);
      f16x2 p3 = pkrtz(a1[2], a1[3]);
      fa = (f16x8){p0[0], p0[1], p1[0], p1[1], p2[0], p2[1], p3[0], p3[1]};
    }
    f32x4 b0 = *(const f32x4*)(wrow + kb);
    f32x4 b1 = *(const f32x4*)(wrow + kb + 4);
    f16x2 q0 = pkrtz(b0[0], b0[1]);
    f16x2 q1 = pkrtz(b0[2], b0[3]);
    f16x2 q2 = pkrtz(b1[0], b1[1]);
    f16x2 q3 = pkrtz(b1[2], b1[3]);
    f16x8 fb = {q0[0], q0[1], q1[0], q1[1], q2[0], q2[1], q3[0], q3[1]};
    acc = __builtin_amdgcn_mfma_f32_16x16x32_f16(fa, fb, acc, 0, 0, 0);
  }
  const float bv = b[n0 + r];
#pragma unroll
  for (int i = 0; i < 4; i++) {
    out[(size_t)(m0 + q * 4 + i) * HDIM + n0 + r] = acc[i] + bv;
  }
}

// ---------------- step 0: h_0 = tanh(U[0]) (h_init = 0) ----------------------
__global__ void step0_kernel(float* __restrict__ out) {
  int i = blockIdx.x * blockDim.x + threadIdx.x;
  out[i] = tanhf(out[i]);
}

// ---------------- step t: out[t] = tanh(out[t] + W_hh @ out[t-1]) ------------
// grid = 8192/16 = 512 blocks x 1024 thr (16 waves); wave per output row.
// h_prev staged to LDS (fp16 on fast path: f16x8 reads are 16B/lane
// contiguous -> conflict-free). W row read 1KiB contiguous per wave-instr.
template <bool WF16>
__global__ __launch_bounds__(1024) void step_kernel(const void* __restrict__ Wv,
                                                    float* __restrict__ out,
                                                    int t) {
  __shared__ typename std::conditional<WF16, f16, float>::type hs[HDIM];
  const float* hprev = out + (size_t)(t - 1) * HDIM;
  {
    const f32x4* hp4 = (const f32x4*)hprev;
    const int tid = threadIdx.x;
#pragma unroll
    for (int i = 0; i < HDIM / 4 / 1024; i++) {  // 2 iters
      const int idx = i * 1024 + tid;
      f32x4 v = hp4[idx];
      if constexpr (WF16) {
        f16x4 hh;
        hh[0] = (f16)v[0]; hh[1] = (f16)v[1];
        hh[2] = (f16)v[2]; hh[3] = (f16)v[3];
        *(f16x4*)&hs[idx * 4] = hh;
      } else {
        *(f32x4*)&hs[idx * 4] = v;
      }
    }
  }
  __syncthreads();

  const int wave = threadIdx.x >> 6;
  const int lane = threadIdx.x & 63;
  const int j = blockIdx.x * 16 + wave;
  float acc = 0.f;

  if constexpr (WF16) {
    const f16* wrow = (const f16*)Wv + (size_t)j * HDIM;
#pragma unroll 4
    for (int it = 0; it < 16; it++) {
      const int kb = it * 512 + lane * 8;
      f16x8 w = *(const f16x8*)(wrow + kb);
      f16x8 h = *(const f16x8*)&hs[kb];
      acc = dot2acc(w[0], w[1], h[0], h[1], acc);
      acc = dot2acc(w[2], w[3], h[2], h[3], acc);
      acc = dot2acc(w[4], w[5], h[4], h[5], acc);
      acc = dot2acc(w[6], w[7], h[6], h[7], acc);
    }
  } else {
    const float* wrow = (const float*)Wv + (size_t)j * HDIM;
#pragma unroll 4
    for (int it = 0; it < 16; it++) {
      const int kb = it * 512 + lane * 8;
      f32x4 w0 = *(const f32x4*)(wrow + kb);
      f32x4 w1 = *(const f32x4*)(wrow + kb + 4);
      const float* hp = (const float*)&hs[kb];
      acc += w0[0] * hp[0] + w0[1] * hp[1] + w0[2] * hp[2] + w0[3] * hp[3];
      acc += w1[0] * hp[4] + w1[1] * hp[5] + w1[2] * hp[6] + w1[7 - 7 + 7] * hp[7];
    }
  }
#pragma unroll
  for (int off = 32; off >= 1; off >>= 1) acc += __shfl_down(acc, off, 64);
  if (lane == 0) {
    const float u = out[(size_t)t * HDIM + j];  // U[t][j] still lives here
    out[(size_t)t * HDIM + j] = tanhf(u + acc);
  }
}

// -----------------------------------------------------------------------------
extern "C" void kernel_launch(void* const* d_in, const int* in_sizes, int n_in,
                              void* d_out, int out_size, void* d_ws,
                              size_t ws_size, hipStream_t stream) {
  const float* x = (const float*)d_in[0];
  const float* Wih = (const float*)d_in[1];
  const float* Whh = (const float*)d_in[2];
  const float* b = (const float*)d_in[3];
  float* out = (float*)d_out;

  const size_t needW = (size_t)HDIM * HDIM * sizeof(f16);  // 128 MiB
  const size_t needX = (size_t)NSTEP * HDIM * sizeof(f16); // 1 MiB
  const bool fast = ws_size >= needW + needX;

  if (fast) {
    f16* w16 = (f16*)d_ws;
    f16* x16 = (f16*)((char*)d_ws + needW);
    cvt_f16_kernel<<<4096, 256, 0, stream>>>(Whh, w16, HDIM * HDIM / 4);
    cvt_f16_kernel<<<64, 256, 0, stream>>>(x, x16, NSTEP * HDIM / 4);
    gemm_u_kernel<true><<<HDIM / 16, 256, 0, stream>>>(x, x16, Wih, b, out);
    step0_kernel<<<HDIM / 256, 256, 0, stream>>>(out);
    for (int t = 1; t < NSTEP; t++)
      step_kernel<true><<<HDIM / 16, 1024, 0, stream>>>((const void*)w16, out, t);
  } else {
    gemm_u_kernel<false><<<HDIM / 16, 256, 0, stream>>>(x, nullptr, Wih, b, out);
    step0_kernel<<<HDIM / 256, 256, 0, stream>>>(out);
    for (int t = 1; t < NSTEP; t++)
      step_kernel<false><<<HDIM / 16, 1024, 0, stream>>>((const void*)Whh, out, t);
  }
}